// Round 12
// baseline (1648.389 us; speedup 1.0000x reference)
//
#include <hip/hip_runtime.h>

// ---------------- problem constants ----------------
#define T_SEQ 80
#define NB    5120
#define NBH   (NB * 256)
#define NVOC  100

// ---------------- ws layout (bytes), total ~17.7 MB ----------------
#define OFF_TABLE0 0u          // 100*1024*4 = 409600 (f32, np-packed)
#define OFF_BIAS1  409600u     // 1024*4     = 4096
#define OFF_BPACK  413696u     // 786432*2   = 1572864 (bf16 frag-layout weights)
#define OFF_RING0  1986560u    // 2 slots bf16 [5120][256] = 5242880
#define OFF_RING1  7229440u    // 2 slots bf16             = 5242880
#define OFF_C0     12472320u   // _Float16, c4 layout      = 2621440
#define OFF_C1     15093760u   // _Float16, c4 layout      = 2621440

// LDS: Ab 3x12800 + Bb 3x8192 + xs 640 = 63616
#define SMEM_BYTES 63616

typedef float  f32x4  __attribute__((ext_vector_type(4)));
typedef __bf16 bf16x8 __attribute__((ext_vector_type(8)));
typedef short  s16x8  __attribute__((ext_vector_type(8)));
typedef _Float16 f16x4 __attribute__((ext_vector_type(4)));
typedef unsigned short u16x8 __attribute__((ext_vector_type(8)));

// column permutation: np -> original gate-major row (i,f,g,o blocks of 256)
__device__ __forceinline__ int colmap(int np) {
  int gate = (np >> 4) & 3;
  int j    = ((np >> 6) << 4) | (np & 15);
  return gate * 256 + j;
}

__device__ __forceinline__ unsigned short f2bf(float f) {
  unsigned int u = __float_as_uint(f);
  u += 0x7fffu + ((u >> 16) & 1u);   // RNE
  return (unsigned short)(u >> 16);
}
__device__ __forceinline__ float bf2f(unsigned short s) {
  return __uint_as_float(((unsigned int)s) << 16);
}
__device__ __forceinline__ float sigm(float x) {
  x = fminf(fmaxf(x, -20.f), 20.f);
  return 1.f / (1.f + __expf(-x));
}
__device__ __forceinline__ float tanh_(float x) {
  x = fminf(fmaxf(x, -10.f), 10.f);
  float e = __expf(2.f * x);
  return (e - 1.f) / (e + 1.f);
}

// ---------------- prep: table + bias + bf16 weight pack (same as R10/R11) ----------------
__global__ void prep_kernel(const float* __restrict__ emb,
                            const float* __restrict__ w_ih0, const float* __restrict__ w_hh0,
                            const float* __restrict__ b_ih0, const float* __restrict__ b_hh0,
                            const float* __restrict__ w_ih1, const float* __restrict__ w_hh1,
                            const float* __restrict__ b_ih1, const float* __restrict__ b_hh1,
                            float* __restrict__ table0, float* __restrict__ bias1,
                            unsigned short* __restrict__ Bpack) {
  int idx = blockIdx.x * 256 + threadIdx.x;
  if (idx < 102400) {
    int v = idx >> 10, np = idx & 1023;
    int row = colmap(np);
    float s = b_ih0[row] + b_hh0[row];
#pragma unroll
    for (int e = 0; e < 8; ++e) s = fmaf(emb[v * 8 + e], w_ih0[row * 8 + e], s);
    table0[idx] = s;
  } else if (idx < 103424) {
    int np = idx - 102400;
    bias1[np] = b_ih1[colmap(np)] + b_hh1[colmap(np)];
  } else {
    int i2 = idx - 103424;               // < 786432
    int i    = i2 & 7;
    int t    = (i2 >> 3) & 511;
    int ni   = (i2 >> 12) & 7;
    int slot = i2 >> 15;                 // 0..23
    int np   = ni * 128 + ((t >> 6) << 4) + (t & 15);
    int row  = colmap(np);
    int k    = (((t & 63) >> 4) << 3) + i;
    float val;
    if (slot < 8) {
      val = w_hh0[row * 256 + slot * 32 + k];
    } else {
      int kc = slot - 8;
      const float* W = (kc < 8) ? w_ih1 : w_hh1;
      val = W[row * 256 + (kc & 7) * 32 + k];
    }
    Bpack[i2] = f2bf(val);
  }
}

// ---------------- per-step kernel ----------------
// Grid 512: p -> (xcd=p&7, idx=p>>3). idx<32: L0(t=s); else L1(t=s-1).
// Tile [160 x 128], 256 thr = 4 waves (2m x 2n), wave [80 x 64].
// 3-deep LDS ring, loads issued 2 granules ahead (two register staging sets).
__global__ __launch_bounds__(256, 1) void step_kernel(
    int s, const int* __restrict__ x,
    const float* __restrict__ table0, const float* __restrict__ bias1,
    const unsigned short* __restrict__ Bpack,
    unsigned short* __restrict__ ring0, unsigned short* __restrict__ ring1,
    _Float16* __restrict__ c0h, _Float16* __restrict__ c1h) {
  extern __shared__ char smem[];
  char* Ab = smem;            // [3][160*80]
  char* Bb = smem + 38400;    // [3][512*16]
  int*  xs = (int*)(smem + 62976);   // [160]

  const int tid = threadIdx.x;
  const int lane = tid & 63, wid = tid >> 6;
  const int l15 = lane & 15, lhi = lane >> 4;
  const int wm = wid >> 1, wn = wid & 1, rw = wm * 80;

  const int p = blockIdx.x;
  const int xcd = p & 7, idx = p >> 3;
  const bool isL0 = idx < 32;
  const int sub = idx & 31;
  const int mi = xcd * 4 + (sub >> 3);
  const int ni = sub & 7;
  const int rows = mi * 160;

  int t;
  if (isL0) { if (s == T_SEQ) return; t = s; }
  else      { if (s == 0)     return; t = s - 1; }

  const unsigned short* ring0Prev = ring0 + ((s + 1) & 1) * NBH;  // h0(s-1)
  unsigned short*       ring0Cur  = ring0 + (s & 1) * NBH;        // h0(s)
  const unsigned short* h1Prev    = ring1 + (s & 1) * NBH;        // h1(s-2)
  unsigned short*       h1Cur     = ring1 + ((s + 1) & 1) * NBH;  // h1(s-1)

  const int KC = isL0 ? (t > 0 ? 8 : 0) : (t > 0 ? 16 : 8);

  // stage x tile (L0 only): coalesced, consumed by epilogue via LDS broadcast
  if (isL0 && tid < 160) xs[tid] = x[t * NB + rows + tid];

  f32x4 acc[5][4];
#pragma unroll
  for (int m = 0; m < 5; ++m)
#pragma unroll
    for (int nf = 0; nf < 4; ++nf) acc[m][nf] = (f32x4)0.f;

  // two register staging sets (A: 3x uint4, B: 2x s16x8 each)
  uint4 auA0, auA1, auA2, auB0, auB1, auB2;
  s16x8 bsA0, bsA1, bsB0, bsB1;

#define LOADR(S, kc_) do { \
    const unsigned short* _As; int _ko; \
    if (isL0) { _As = ring0Prev; _ko = (kc_) * 32; } \
    else { _As = ((kc_) < 8) ? ring0Prev : h1Prev; _ko = ((kc_) & 7) * 32; } \
    { int _c = tid;       au##S##0 = *(const uint4*)(_As + (rows + (_c >> 2)) * 256 + _ko + ((_c & 3) << 3)); } \
    { int _c = tid + 256; au##S##1 = *(const uint4*)(_As + (rows + (_c >> 2)) * 256 + _ko + ((_c & 3) << 3)); } \
    if (tid < 128) { int _c = tid + 512; au##S##2 = *(const uint4*)(_As + (rows + (_c >> 2)) * 256 + _ko + ((_c & 3) << 3)); } \
    int _slot = isL0 ? (kc_) : (8 + (kc_)); \
    bs##S##0 = *(const s16x8*)(Bpack + (((_slot * 8 + ni) * 512 + tid) << 3)); \
    bs##S##1 = *(const s16x8*)(Bpack + (((_slot * 8 + ni) * 512 + tid + 256) << 3)); \
  } while (0)

#define STORER(S, ob_) do { \
    char* _ab = Ab + (ob_) * 12800; \
    *(uint4*)(_ab + (tid >> 2) * 80 + (tid & 3) * 16) = au##S##0; \
    { int _c = tid + 256; *(uint4*)(_ab + (_c >> 2) * 80 + (_c & 3) * 16) = au##S##1; } \
    if (tid < 128) { int _c = tid + 512; *(uint4*)(_ab + (_c >> 2) * 80 + (_c & 3) * 16) = au##S##2; } \
    char* _bb = Bb + (ob_) * 8192; \
    *(s16x8*)(_bb + tid * 16) = bs##S##0; \
    *(s16x8*)(_bb + (tid + 256) * 16) = bs##S##1; \
  } while (0)

#define CONSUME(ob_) do { \
    const char* _ab = Ab + (ob_) * 12800; \
    const char* _bp = Bb + (ob_) * 8192; \
    bf16x8 _bld[4]; \
    _Pragma("unroll") \
    for (int _nf = 0; _nf < 4; ++_nf) \
      _bld[_nf] = *(const bf16x8*)(_bp + ((wn * 4 + _nf) * 64 + lane) * 16); \
    _Pragma("unroll") \
    for (int _m = 0; _m < 5; ++_m) { \
      bf16x8 _a = *(const bf16x8*)(_ab + (rw + _m * 16 + l15) * 80 + lhi * 16); \
      _Pragma("unroll") \
      for (int _nf = 0; _nf < 4; ++_nf) \
        acc[_m][_nf] = __builtin_amdgcn_mfma_f32_16x16x32_bf16(_a, _bld[_nf], acc[_m][_nf], 0, 0, 0); \
    } \
  } while (0)

  if (KC > 0) {
    LOADR(A, 0);
    LOADR(B, 1);
    STORER(A, 0);
    int bufc = 0;
#pragma unroll 1
    for (int kc = 0; kc < KC; kc += 2) {
      const int b1 = (bufc + 1) % 3, b2 = (bufc + 2) % 3;
      __syncthreads();                       // publishes buf[bufc]
      if (kc + 2 < KC) LOADR(A, kc + 2);     // 2-ahead prefetch into set A
      CONSUME(bufc);
      STORER(B, b1);                         // granule kc+1 -> buf b1
      __syncthreads();                       // publishes buf[b1]
      if (kc + 3 < KC) LOADR(B, kc + 3);     // 2-ahead prefetch into set B
      CONSUME(b1);
      if (kc + 2 < KC) STORER(A, b2);        // granule kc+2 -> buf b2
      bufc = b2;
    }
  } else {
    __syncthreads();                         // publish xs (s==0 L0 path)
  }

  // ---------------- epilogue: LSTM cell update ----------------
  const int jh = (ni * 2 + wn) * 16 + l15;          // h-column
  if (isL0) {
    const int tbb = ni * 128 + wn * 64 + l15;
#pragma unroll
    for (int m = 0; m < 5; ++m) {
      const int cbase = ((rows + rw + m * 16) >> 2) + lhi;   // c4 row-group
      f16x4 cold4 = (f16x4)(_Float16)0.f;
      if (t > 0) cold4 = *(const f16x4*)(c0h + cbase * 1024 + jh * 4);
      f16x4 cnew;
#pragma unroll
      for (int r = 0; r < 4; ++r) {
        int rowl = rw + m * 16 + lhi * 4 + r;
        const float* tb = table0 + xs[rowl] * 1024 + tbb;
        float gi = acc[m][0][r] + tb[0];
        float gf = acc[m][1][r] + tb[16];
        float gg = acc[m][2][r] + tb[32];
        float go = acc[m][3][r] + tb[48];
        float cn = sigm(gf) * (float)cold4[r] + sigm(gi) * tanh_(gg);
        cnew[r] = (_Float16)cn;
        ring0Cur[(rows + rowl) * 256 + jh] = f2bf(sigm(go) * tanh_(cn));
      }
      *(f16x4*)(c0h + cbase * 1024 + jh * 4) = cnew;
    }
  } else {
    const int bbb = ni * 128 + wn * 64 + l15;
    float b0 = bias1[bbb], b1 = bias1[bbb + 16], b2 = bias1[bbb + 32], b3 = bias1[bbb + 48];
#pragma unroll
    for (int m = 0; m < 5; ++m) {
      const int cbase = ((rows + rw + m * 16) >> 2) + lhi;
      f16x4 cold4 = (f16x4)(_Float16)0.f;
      if (t > 0) cold4 = *(const f16x4*)(c1h + cbase * 1024 + jh * 4);
      f16x4 cnew;
#pragma unroll
      for (int r = 0; r < 4; ++r) {
        int rowl = rw + m * 16 + lhi * 4 + r;
        float gi = acc[m][0][r] + b0;
        float gf = acc[m][1][r] + b1;
        float gg = acc[m][2][r] + b2;
        float go = acc[m][3][r] + b3;
        float cn = sigm(gf) * (float)cold4[r] + sigm(gi) * tanh_(gg);
        cnew[r] = (_Float16)cn;
        h1Cur[(rows + rowl) * 256 + jh] = f2bf(sigm(go) * tanh_(cn));
      }
      *(f16x4*)(c1h + cbase * 1024 + jh * 4) = cnew;
    }
  }
#undef LOADR
#undef STORER
#undef CONSUME
}

// ---------------- decoder: wave-per-v, fully coalesced dec_w streams ----------------
// 512 blocks: r = b>>3, qoff = (b&7)*2560. hs[2560] f32 in LDS.
// Wave w handles v = w, w+4, ...: lanes stride q by 4 floats -> 1KB/wave coalesced.
__global__ __launch_bounds__(256) void decoder_kernel(
    const unsigned short* __restrict__ h1, const float* __restrict__ dec_w,
    const float* __restrict__ dec_b, float* __restrict__ out) {
  __shared__ float hs[2560];
  const int tid = threadIdx.x, lane = tid & 63, wid = tid >> 6;
  const int b = blockIdx.x;
  const int r = b >> 3;
  const int qoff = (b & 7) * 2560;

  const unsigned short* src = h1 + (size_t)b * 2560;
  for (int i = tid; i < 320; i += 256) {
    u16x8 v8 = *(const u16x8*)(src + i * 8);
#pragma unroll
    for (int e = 0; e < 8; ++e) hs[i * 8 + e] = bf2f(v8[e]);
  }
  __syncthreads();

  for (int vv = wid; vv < NVOC; vv += 4) {
    const float* wp = dec_w + (size_t)vv * 20480 + qoff + lane * 4;
    const float* hp = hs + lane * 4;
    float s = 0.f;
#pragma unroll
    for (int it = 0; it < 10; ++it) {
      f32x4 w4 = *(const f32x4*)(wp + it * 256);
      f32x4 h4 = *(const f32x4*)(hp + it * 256);
      s += w4[0] * h4[0] + w4[1] * h4[1] + w4[2] * h4[2] + w4[3] * h4[3];
    }
#pragma unroll
    for (int off = 32; off > 0; off >>= 1) s += __shfl_down(s, off, 64);
    if (lane == 0) {
      if ((b & 7) == 0) s += dec_b[vv];
      atomicAdd(&out[r * 100 + vv], s);
    }
  }
}

// ---------------- host launch: prep + 81 step kernels + decoder ----------------
extern "C" void kernel_launch(void* const* d_in, const int* in_sizes, int n_in,
                              void* d_out, int out_size, void* d_ws, size_t ws_size,
                              hipStream_t stream) {
  const int*   x     = (const int*)d_in[0];
  const float* emb   = (const float*)d_in[1];
  const float* w_ih0 = (const float*)d_in[2];
  const float* w_hh0 = (const float*)d_in[3];
  const float* b_ih0 = (const float*)d_in[4];
  const float* b_hh0 = (const float*)d_in[5];
  const float* w_ih1 = (const float*)d_in[6];
  const float* w_hh1 = (const float*)d_in[7];
  const float* b_ih1 = (const float*)d_in[8];
  const float* b_hh1 = (const float*)d_in[9];
  const float* dec_w = (const float*)d_in[10];
  const float* dec_b = (const float*)d_in[11];
  float* out = (float*)d_out;
  char* ws = (char*)d_ws;

  float*          table0 = (float*)(ws + OFF_TABLE0);
  float*          bias1  = (float*)(ws + OFF_BIAS1);
  unsigned short* Bpack  = (unsigned short*)(ws + OFF_BPACK);
  unsigned short* ring0  = (unsigned short*)(ws + OFF_RING0);
  unsigned short* ring1  = (unsigned short*)(ws + OFF_RING1);
  _Float16*       c0h    = (_Float16*)(ws + OFF_C0);
  _Float16*       c1h    = (_Float16*)(ws + OFF_C1);

  hipMemsetAsync(out, 0, (size_t)out_size * 4, stream);
  prep_kernel<<<3476, 256, 0, stream>>>(emb, w_ih0, w_hh0, b_ih0, b_hh0,
                                        w_ih1, w_hh1, b_ih1, b_hh1,
                                        table0, bias1, Bpack);
  hipFuncSetAttribute((const void*)step_kernel,
                      hipFuncAttributeMaxDynamicSharedMemorySize, SMEM_BYTES);
  for (int s = 0; s <= T_SEQ; ++s)
    step_kernel<<<512, 256, SMEM_BYTES, stream>>>(s, x, table0, bias1, Bpack,
                                                  ring0, ring1, c0h, c1h);
  decoder_kernel<<<512, 256, 0, stream>>>(ring1 + NBH, dec_w, dec_b, out);
}